// Round 1
// 56.612 us; speedup vs baseline: 1.0517x; 1.0517x over previous
//
#include <hip/hip_runtime.h>

// out[j,i] = sum_k exp(-(x_k - i/512)^2 * 5000) * exp(-(y_k - j/512)^2 * 5000)
// sigma = 0.01 -> 5.12 px: a point only influences +/-33 px (tail < 1e-9).
//
// v2: 16x16 tiles (grid 32x32 = 1024 blocks) instead of 32x32 (256 blocks).
// The previous version ran 1 block/CU = 1 wave/SIMD: every LDS latency,
// barrier and exp chain was fully latency-exposed and empty tiles left CUs
// idle. 1024 blocks gives ~4 blocks/CU (16 waves/CU) for latency hiding and
// backfill, and quarters the per-block critical path (CH=32 chunks, 1 px
// per thread, dual accumulators).
// Sparse gather: evaluate all 1024 Bezier points per block, cull to the
// tile's +/-33px window, wave-ballot compaction into LDS (1 atomic/wave),
// sentinel-pad to a CH multiple so staging + accumulate are branch-free.
// Single dispatch, direct full-coverage store (empty tiles: Mp==0 -> acc=0).

constexpr int RES_ = 512;
constexpr int TILE = 16;               // output tile edge
constexpr int NPTS = 1024;
constexpr int CH   = 32;               // points staged per chunk
constexpr float RAD = 33.0f / 512.0f;  // truncation radius (33 px)
constexpr float SENTINEL = 1.0e3f;     // far away -> exp flushes to exact 0

__global__ __launch_bounds__(256)
void bezier_sparse16(const float* __restrict__ curves, float* __restrict__ out) {
    __shared__ float lx[NPTS + CH], ly[NPTS + CH];   // compacted + pad (8.4 KB)
    __shared__ int count;
    __shared__ __align__(16) float ex_s[CH][TILE];   // 2 KB
    __shared__ __align__(16) float ey_s[CH][TILE];   // 2 KB

    const int tid  = threadIdx.x;
    const int lane = tid & 63;
    const int ibase = blockIdx.x * TILE;   // output columns i
    const int jbase = blockIdx.y * TILE;   // output rows j

    if (tid == 0) count = 0;
    __syncthreads();

    const float xlo = (float)ibase * (1.0f/512.0f) - RAD;
    const float xhi = (float)(ibase + TILE - 1) * (1.0f/512.0f) + RAD;
    const float ylo = (float)jbase * (1.0f/512.0f) - RAD;
    const float yhi = (float)(jbase + TILE - 1) * (1.0f/512.0f) + RAD;

    // --- evaluate 4 Bezier points/thread (de Casteljau), ballot-compact ---
#pragma unroll
    for (int e = 0; e < NPTS / 256; ++e) {
        int p = e * 256 + tid;
        int c = p >> 7;                            // curve 0..7
        float t = (float)(p & 127) * (1.0f / 127.0f);
        const float* cp = curves + c * 8;
        float p0x = cp[0], p0y = cp[1];
        float p1x = cp[2], p1y = cp[3];
        float p2x = cp[4], p2y = cp[5];
        float p3x = cp[6], p3y = cp[7];
        float a01x = p0x + (p1x - p0x) * t, a01y = p0y + (p1y - p0y) * t;
        float a12x = p1x + (p2x - p1x) * t, a12y = p1y + (p2y - p1y) * t;
        float a23x = p2x + (p3x - p2x) * t, a23y = p2y + (p3y - p2y) * t;
        float qax = a01x + (a12x - a01x) * t, qay = a01y + (a12y - a01y) * t;
        float qbx = a12x + (a23x - a12x) * t, qby = a12y + (a23y - a12y) * t;
        float X = qax + (qbx - qax) * t;
        float Y = qay + (qby - qay) * t;

        bool keep = (X > xlo && X < xhi && Y > ylo && Y < yhi);
        unsigned long long mask = __ballot(keep);
        if (mask) {
            int nsurv  = __popcll(mask);
            int prefix = __popcll(mask & ((1ull << lane) - 1ull));
            int leader = __ffsll((long long)mask) - 1;
            int base_i = 0;
            if (lane == leader)
                base_i = atomicAdd(&count, nsurv);      // 1 atomic per wave
            base_i = __shfl(base_i, leader);
            if (keep) {
                lx[base_i + prefix] = X;
                ly[base_i + prefix] = Y;
            }
        }
    }
    __syncthreads();
    const int M = count;

    // --- sentinel-pad survivor list up to next CH multiple (branch-free) ---
    if (tid < CH) {
        lx[M + tid] = SENTINEL;
        ly[M + tid] = SENTINEL;
    }
    __syncthreads();

    // one output pixel per thread
    const int it = tid & 15, jt = tid >> 4;
    float acc0 = 0.f, acc1 = 0.f;

    const int Mp = (M + CH - 1) & ~(CH - 1);       // padded chunk count
    for (int base = 0; base < Mp; base += CH) {
        // --- stage exp factors: CH x TILE slots, branch-free, 4/thread ---
#pragma unroll
        for (int e = 0; e < (CH * TILE) / 256; ++e) {
            int idx = e * 256 + tid;
            int kk  = idx >> 4;                    // TILE == 16
            int ii  = idx & 15;
            float xv = lx[base + kk], yv = ly[base + kk];
            float dx = xv - (float)(ibase + ii) * (1.0f / 512.0f);
            float dy = yv - (float)(jbase + ii) * (1.0f / 512.0f);
            ex_s[kk][ii] = __expf(dx * dx * -5000.0f);   // sentinel -> 0
            ey_s[kk][ii] = __expf(dy * dy * -5000.0f);
        }
        __syncthreads();

        // --- rank-1 accumulate, fixed trip count, dual accumulators ---
#pragma unroll
        for (int k = 0; k < CH; k += 2) {
            acc0 = fmaf(ey_s[k][jt],     ex_s[k][it],     acc0);
            acc1 = fmaf(ey_s[k + 1][jt], ex_s[k + 1][it], acc1);
        }
        __syncthreads();                           // protect ex_s/ey_s reuse
    }

    // --- full-coverage store (empty tiles write 0, no memset needed) ---
    out[(size_t)(jbase + jt) * RES_ + (ibase + it)] = acc0 + acc1;
}

extern "C" void kernel_launch(void* const* d_in, const int* in_sizes, int n_in,
                              void* d_out, int out_size, void* d_ws, size_t ws_size,
                              hipStream_t stream) {
    const float* curves = (const float*)d_in[0];
    float* out = (float*)d_out;

    dim3 grid(RES_ / TILE, RES_ / TILE);           // (32, 32) = 1024 blocks
    bezier_sparse16<<<grid, dim3(256), 0, stream>>>(curves, out);
}